// Round 8
// baseline (305.468 us; speedup 1.0000x reference)
//
#include <hip/hip_runtime.h>

typedef unsigned short ushort_t;
typedef unsigned int uint_t;
typedef __attribute__((ext_vector_type(8))) short short8;
typedef __attribute__((ext_vector_type(4))) float floatx4;

#define QSCALE 0.03187936f  // (1/sqrt(2048)) * log2(e): quirk scale + exp2 fold

__device__ __forceinline__ ushort_t f2bf(float f) {
    union { float f; uint_t u; } c; c.f = f;
    uint_t u = c.u;
    return (ushort_t)((u + 0x7fffu + ((u >> 16) & 1u)) >> 16);  // RNE
}
__device__ __forceinline__ floatx4 mfma16x32(short8 a, short8 b, floatx4 c) {
    return __builtin_amdgcn_mfma_f32_16x16x32_bf16(a, b, c, 0, 0, 0);
}
__device__ __forceinline__ floatx4 zero4() { floatx4 z = {0.f, 0.f, 0.f, 0.f}; return z; }

// Async 16B global->LDS. Per-lane lds ptr = base + lane*16B slot (HW uses
// lane0's ptr as wave base and strides lane*16 — matches our linear slots).
__device__ __forceinline__ void gload16(const ushort_t* g, ushort_t* l) {
    __builtin_amdgcn_global_load_lds(
        (const __attribute__((address_space(1))) void*)g,
        (__attribute__((address_space(3))) void*)l, 16, 0, 0);
}

// ---------------------------------------------------------------------------
// f32 -> bf16 convert (RNE), 8 elems/thread, up to 3 tensors of 4M elems.
// ---------------------------------------------------------------------------
__global__ __launch_bounds__(256) void cvt_bf16(
    const float* __restrict__ s0, const float* __restrict__ s1,
    const float* __restrict__ s2, ushort_t* __restrict__ d0,
    ushort_t* __restrict__ d1, ushort_t* __restrict__ d2)
{
    const int which = blockIdx.x >> 11;
    const int blk = blockIdx.x & 2047;
    const float* src = (which == 0) ? s0 : (which == 1) ? s1 : s2;
    ushort_t* dst = (which == 0) ? d0 : (which == 1) ? d1 : d2;
    const int i = (blk * 256 + threadIdx.x) * 8;
    float4 f0 = *(const float4*)(src + i);
    float4 f1 = *(const float4*)(src + i + 4);
    __align__(16) ushort_t t[8];
    t[0] = f2bf(f0.x); t[1] = f2bf(f0.y); t[2] = f2bf(f0.z); t[3] = f2bf(f0.w);
    t[4] = f2bf(f1.x); t[5] = f2bf(f1.y); t[6] = f2bf(f1.z); t[7] = f2bf(f1.w);
    *(uint4*)(dst + i) = *(uint4*)t;
}

// ---------------------------------------------------------------------------
// Fused convert+transpose: W[k][j] (1024x1024 f32) -> WT[j][k] bf16.
// ---------------------------------------------------------------------------
__global__ __launch_bounds__(256) void transpose_w(
    const float* __restrict__ W0, const float* __restrict__ W1,
    const float* __restrict__ W2, const float* __restrict__ W3,
    ushort_t* __restrict__ WT)
{
    __shared__ ushort_t tile[64][65];
    const float* W = (blockIdx.y == 0) ? W0 : (blockIdx.y == 1) ? W1
                   : (blockIdx.y == 2) ? W2 : W3;
    ushort_t* dst = WT + (size_t)blockIdx.y * (1024 * 1024);
    const int t = threadIdx.x;
    const int r = t >> 2, p = t & 3;
    const int j0 = (blockIdx.x & 15) << 6, k0 = (blockIdx.x >> 4) << 6;

    const float* src = W + (size_t)(k0 + r) * 1024 + j0 + p * 16;
    float4 f0 = *(const float4*)(src);
    float4 f1 = *(const float4*)(src + 4);
    float4 f2 = *(const float4*)(src + 8);
    float4 f3 = *(const float4*)(src + 12);
    ushort_t* tr = &tile[r][p * 16];
    tr[0] = f2bf(f0.x); tr[1] = f2bf(f0.y); tr[2]  = f2bf(f0.z); tr[3]  = f2bf(f0.w);
    tr[4] = f2bf(f1.x); tr[5] = f2bf(f1.y); tr[6]  = f2bf(f1.z); tr[7]  = f2bf(f1.w);
    tr[8] = f2bf(f2.x); tr[9] = f2bf(f2.y); tr[10] = f2bf(f2.z); tr[11] = f2bf(f2.w);
    tr[12] = f2bf(f3.x); tr[13] = f2bf(f3.y); tr[14] = f2bf(f3.z); tr[15] = f2bf(f3.w);
    __syncthreads();
    __align__(16) ushort_t buf[16];
#pragma unroll
    for (int i = 0; i < 16; ++i) buf[i] = tile[p * 16 + i][r];
    ushort_t* o = dst + (size_t)(j0 + r) * 1024 + k0 + p * 16;
    *(uint4*)(o)     = *(uint4*)(buf);
    *(uint4*)(o + 8) = *(uint4*)(buf + 8);
}

// ---------------------------------------------------------------------------
// GEMM, 64x128 tile (512 blocks/matrix -> >=2 blocks/CU on every launch):
// C[r][c] = sum_k A[r][k]*WT[c][k] + bias[c].  M=4096, N=1024, K=1024.
// BK=32, global_load_lds staging, XOR-swizzled LDS chunks.
// mode = blockIdx.z + zbase: 0: Q -> bf16 [B,H,S,64] *QSCALE;
// 1: K -> bf16 [B,H,S,64]; 2: V -> bf16 [B,H,64,S]; 3: out -> f32 [r][c].
// ---------------------------------------------------------------------------
__global__ __launch_bounds__(256) void gemm_nt64(
    const ushort_t* __restrict__ A0, const ushort_t* __restrict__ A1,
    const ushort_t* __restrict__ A2, const ushort_t* __restrict__ A3,
    const ushort_t* __restrict__ WT,
    const float* __restrict__ b0, const float* __restrict__ b1,
    const float* __restrict__ b2, const float* __restrict__ b3,
    ushort_t* __restrict__ Dq, ushort_t* __restrict__ Dk,
    ushort_t* __restrict__ Dv, float* __restrict__ Dout, int zbase)
{
    __shared__ __align__(16) ushort_t As[64 * 32];
    __shared__ __align__(16) ushort_t Bs[128 * 32];

    const int mode = blockIdx.z + zbase;
    const ushort_t* A = (mode == 0) ? A0 : (mode == 1) ? A1 : (mode == 2) ? A2 : A3;
    const float* bias = (mode == 0) ? b0 : (mode == 1) ? b1 : (mode == 2) ? b2 : b3;
    const ushort_t* Bt = WT + (size_t)mode * 1048576;

    const int tid = threadIdx.x;
    const int lane = tid & 63, wid = tid >> 6;
    const int quad = lane >> 4, l16 = lane & 15;
    const int wm = wid >> 1, wn = wid & 1;
    const int row0 = blockIdx.y << 6, col0 = blockIdx.x << 7;

    floatx4 acc[2][4];
#pragma unroll
    for (int i = 0; i < 2; ++i)
#pragma unroll
        for (int j = 0; j < 4; ++j) acc[i][j] = zero4();

    const int rA = tid >> 2, cA = (tid & 3) ^ (rA & 3);
    const ushort_t* gA = A + (size_t)(row0 + rA) * 1024 + cA * 8;
    ushort_t* lA = As + tid * 8;
    const int i0 = tid, i1 = 256 + tid;
    const int rB0 = i0 >> 2, cB0 = (i0 & 3) ^ (rB0 & 3);
    const int rB1 = i1 >> 2, cB1 = (i1 & 3) ^ (rB1 & 3);
    const ushort_t* gB0 = Bt + (size_t)(col0 + rB0) * 1024 + cB0 * 8;
    const ushort_t* gB1 = Bt + (size_t)(col0 + rB1) * 1024 + cB1 * 8;
    ushort_t* lB0 = Bs + i0 * 8;  ushort_t* lB1 = Bs + i1 * 8;

    const int sa_off = (quad ^ (l16 & 3)) * 8;

    for (int k0 = 0; k0 < 1024; k0 += 32) {
        __syncthreads();
        gload16(gA + k0, lA);
        gload16(gB0 + k0, lB0);
        gload16(gB1 + k0, lB1);
        __syncthreads();

        short8 af[2], bf[4];
#pragma unroll
        for (int i = 0; i < 2; ++i)
            af[i] = *(const short8*)(As + (wm * 32 + i * 16 + l16) * 32 + sa_off);
#pragma unroll
        for (int j = 0; j < 4; ++j)
            bf[j] = *(const short8*)(Bs + (wn * 64 + j * 16 + l16) * 32 + sa_off);
#pragma unroll
        for (int i = 0; i < 2; ++i)
#pragma unroll
            for (int j = 0; j < 4; ++j)
                acc[i][j] = mfma16x32(af[i], bf[j], acc[i][j]);
    }

    const float sc = (mode == 0) ? QSCALE : 1.f;
#pragma unroll
    for (int i = 0; i < 2; ++i) {
#pragma unroll
        for (int j = 0; j < 4; ++j) {
            const int c = col0 + wn * 64 + j * 16 + l16;
            const float bv = bias[c];
#pragma unroll
            for (int rr = 0; rr < 4; ++rr) {
                const int r = row0 + wm * 32 + i * 16 + quad * 4 + rr;
                const float v = (acc[i][j][rr] + bv) * sc;
                const int b = r >> 11, s = r & 2047, h = c >> 6, d = c & 63;
                if (mode <= 1) {
                    ushort_t* D = (mode == 0) ? Dq : Dk;
                    D[(((b * 16 + h) * 2048 + s) << 6) + d] = f2bf(v);
                } else if (mode == 2) {
                    Dv[(((b * 16 + h) * 64 + d) << 11) + s] = f2bf(v);
                } else {
                    Dout[(size_t)r * 1024 + c] = v;
                }
            }
        }
    }
}

// ---------------------------------------------------------------------------
// Attention, S^T trick + full-K PV, BK=128 (two 64-col K-tiles per staging
// round -> 16 barrier rounds), XCD-affinity 1D grid: bh = blk & 31 keeps all
// 32 q-blocks of one head on one XCD (2MB K+V working set, L2-resident).
// S^T = K·Q^T: lane (l16,quad) holds P[qrow=l16][kcol=g*16+quad*4+r].
// PV: K=32 MFMA, slots j=0..3 <- g-block 2G, j=4..7 <- g-block 2G+1, on
// both A (packed P) and B (two b64 V reads). Fixed-shift softmax:
// p = exp2(min(s,80)), truncated to bf16, denominator sums truncated values.
// ---------------------------------------------------------------------------
__global__ __launch_bounds__(256, 4) void attn64(
    const ushort_t* __restrict__ Q, const ushort_t* __restrict__ K,
    const ushort_t* __restrict__ Vt, ushort_t* __restrict__ Out)
{
    __shared__ __align__(16) ushort_t Ks[128 * 64];  // [kcol][d]  16KB
    __shared__ __align__(16) ushort_t Vs[64 * 128];  // [d][kcol]  16KB

    const int tid = threadIdx.x;
    const int lane = tid & 63, wid = tid >> 6;
    const int quad = lane >> 4, l16 = lane & 15;
    const int blk = blockIdx.x;
    const int bh = blk & 31;          // head-major: XCD = blk%8 = bh%8
    const int q0 = (blk >> 5) << 6;

    const ushort_t* Qh = Q + (size_t)bh * (2048 * 64);
    const ushort_t* Kh = K + (size_t)bh * (2048 * 64);
    const ushort_t* Vh = Vt + (size_t)bh * (64 * 2048);

    const int qr = q0 + wid * 16 + l16;
    const short8 qf0 = *(const short8*)(Qh + (size_t)qr * 64 + quad * 8);
    const short8 qf1 = *(const short8*)(Qh + (size_t)qr * 64 + 32 + quad * 8);

    float l_st = 0.f;
    floatx4 o_acc[4];
#pragma unroll
    for (int d = 0; d < 4; ++d) o_acc[d] = zero4();

    // staging: K 1024 chunks (128 rows x 8), V 1024 chunks (64 rows x 16);
    // 4 slots/thread each. Slot i holds XOR-swizzled chunk of its row.
    const ushort_t* gK[4]; const ushort_t* gV[4];
    ushort_t *lK[4], *lV[4];
#pragma unroll
    for (int s = 0; s < 4; ++s) {
        const int i = tid + 256 * s;
        const int kr = i >> 3, kc = (i & 7) ^ (kr & 7);
        gK[s] = Kh + (size_t)kr * 64 + kc * 8;
        lK[s] = Ks + i * 8;
        const int dr = i >> 4, cs = i & 15;
        const int cc = (cs & 8) | ((cs & 7) ^ (dr & 7));
        gV[s] = Vh + (size_t)dr * 2048 + cc * 8;
        lV[s] = Vs + i * 8;
    }

    const int l7 = l16 & 7;
    const int q2 = quad >> 1, q1 = (quad & 1) * 4;

    for (int kt = 0; kt < 2048; kt += 128) {
        __syncthreads();
#pragma unroll
        for (int s = 0; s < 4; ++s) {
            gload16(gK[s] + (size_t)kt * 64, lK[s]);
            gload16(gV[s] + kt, lV[s]);
        }
        __syncthreads();

        // S^T: A = K-frag (m=kcol), B = Q-frag (n=qrow); 8 g-blocks of 16 kcols
        floatx4 sa[8];
#pragma unroll
        for (int g = 0; g < 8; ++g) {
            const int row = g * 16 + l16;  // kcol; row&7 == l7
            const short8 kf0 = *(const short8*)(Ks + row * 64 + ((quad ^ l7) * 8));
            const short8 kf1 = *(const short8*)(Ks + row * 64 + (((quad + 4) ^ l7) * 8));
            sa[g] = mfma16x32(kf0, qf0, zero4());
            sa[g] = mfma16x32(kf1, qf1, sa[g]);
        }

        // softmax + PV: two g-blocks per K=32 MFMA
#pragma unroll
        for (int G = 0; G < 4; ++G) {
            uint_t ub[8];
#pragma unroll
            for (int t = 0; t < 8; ++t) {
                const int g = G * 2 + (t >> 2), r = t & 3;
                const float e = __builtin_amdgcn_exp2f(fminf(sa[g][r], 80.f));
                const uint_t u = __float_as_uint(e) & 0xffff0000u;
                l_st += __uint_as_float(u);   // sum the TRUNCATED value
                ub[t] = u;
            }
            union { uint_t u[4]; short8 s; } pc;
            pc.u[0] = (ub[0] >> 16) | ub[1];
            pc.u[1] = (ub[2] >> 16) | ub[3];
            pc.u[2] = (ub[4] >> 16) | ub[5];
            pc.u[3] = (ub[6] >> 16) | ub[7];
            const short8 pf = pc.s;

            // semantic V chunks for kcol group 32G..32G+31
            const int c0 = 4 * G + q2, c1 = 4 * G + 2 + q2;
            const int s0_ = ((c0 & 8) | ((c0 & 7) ^ l7)) * 8 + q1;
            const int s1_ = ((c1 & 8) | ((c1 & 7) ^ l7)) * 8 + q1;
#pragma unroll
            for (int db = 0; db < 4; ++db) {
                const int vbase = (db * 16 + l16) * 128;
                const uint2 v0 = *(const uint2*)(Vs + vbase + s0_);
                const uint2 v1 = *(const uint2*)(Vs + vbase + s1_);
                union { uint_t u[4]; short8 s; } vc;
                vc.u[0] = v0.x; vc.u[1] = v0.y; vc.u[2] = v1.x; vc.u[3] = v1.y;
                o_acc[db] = mfma16x32(pf, vc.s, o_acc[db]);
            }
        }
    }

    // denominator: sum across the 4 quads sharing qrow=l16
    l_st += __shfl_xor(l_st, 16);
    l_st += __shfl_xor(l_st, 32);

    const int b = bh >> 4, h = bh & 15;
    const int s0 = q0 + wid * 16 + quad * 4;
#pragma unroll
    for (int r = 0; r < 4; ++r) {
        const float lr = __shfl(l_st, quad * 4 + r);  // l of qrow quad*4+r
        const float inv = 1.f / lr;
#pragma unroll
        for (int db = 0; db < 4; ++db) {
            const float v = o_acc[db][r] * inv;
            Out[(size_t)(b * 2048 + s0 + r) * 1024 + h * 64 + db * 16 + l16] = f2bf(v);
        }
    }
}

// ---------------------------------------------------------------------------
// Launch.
//  big (>=64MiB): WT@0 Qb@8M Kb@16M Vb@24M Qp@32M Kp@40M Vtp@48M An@56M
//     tp -> cvt3 -> gemm z=3 (1536 blk) -> attn -> gemm z=1 zbase=3
//  small (40MiB): WT@0 buf1@8M buf2@16M Qp@24M Kp@32M
//     tp -> cvt(Q,K) -> gemm z=2 (1024) -> cvt(V) -> gemm z=1 (V)
//        -> attn(->buf1) -> gemm z=1 zbase=3
// ---------------------------------------------------------------------------
extern "C" void kernel_launch(void* const* d_in, const int* in_sizes, int n_in,
                              void* d_out, int out_size, void* d_ws, size_t ws_size,
                              hipStream_t stream) {
    const float* queries = (const float*)d_in[0];
    const float* keys    = (const float*)d_in[1];
    const float* values  = (const float*)d_in[2];
    const float* Wq = (const float*)d_in[3];
    const float* bq = (const float*)d_in[4];
    const float* Wk = (const float*)d_in[5];
    const float* bk = (const float*)d_in[6];
    const float* Wv = (const float*)d_in[7];
    const float* bv = (const float*)d_in[8];
    const float* Wo = (const float*)d_in[9];
    const float* bo = (const float*)d_in[10];
    float* out = (float*)d_out;

    char* ws = (char*)d_ws;
    const size_t MB = 1024 * 1024;
    ushort_t* WT = (ushort_t*)(ws);
    dim3 tb(256);

    transpose_w<<<dim3(256, 4), tb, 0, stream>>>(Wq, Wk, Wv, Wo, WT);

    if (ws_size >= 64 * MB) {
        ushort_t* Qb  = (ushort_t*)(ws + 8 * MB);
        ushort_t* Kb  = (ushort_t*)(ws + 16 * MB);
        ushort_t* Vb  = (ushort_t*)(ws + 24 * MB);
        ushort_t* Qp  = (ushort_t*)(ws + 32 * MB);
        ushort_t* Kp  = (ushort_t*)(ws + 40 * MB);
        ushort_t* Vtp = (ushort_t*)(ws + 48 * MB);
        ushort_t* An  = (ushort_t*)(ws + 56 * MB);
        cvt_bf16<<<dim3(6144), tb, 0, stream>>>(queries, keys, values, Qb, Kb, Vb);
        gemm_nt64<<<dim3(8, 64, 3), tb, 0, stream>>>(Qb, Kb, Vb, An, WT,
            bq, bk, bv, bo, Qp, Kp, Vtp, out, 0);
        attn64<<<dim3(1024), tb, 0, stream>>>(Qp, Kp, Vtp, An);
        gemm_nt64<<<dim3(8, 64, 1), tb, 0, stream>>>(Qb, Kb, Vb, An, WT,
            bq, bk, bv, bo, Qp, Kp, Vtp, out, 3);
    } else {
        ushort_t* buf1 = (ushort_t*)(ws + 8 * MB);
        ushort_t* buf2 = (ushort_t*)(ws + 16 * MB);
        ushort_t* Qp   = (ushort_t*)(ws + 24 * MB);
        ushort_t* Kp   = (ushort_t*)(ws + 32 * MB);
        cvt_bf16<<<dim3(4096), tb, 0, stream>>>(queries, keys, keys, buf1, buf2, buf2);
        gemm_nt64<<<dim3(8, 64, 2), tb, 0, stream>>>(buf1, buf2, buf2, buf2, WT,
            bq, bk, bk, bk, Qp, Kp, Kp, out, 0);
        cvt_bf16<<<dim3(2048), tb, 0, stream>>>(values, values, values, buf1, buf1, buf1);
        gemm_nt64<<<dim3(8, 64, 1), tb, 0, stream>>>(buf1, buf1, buf1, buf1, WT,
            bv, bv, bv, bv, buf2, buf2, buf2, out, 2);   // V -> Vtp = buf2
        attn64<<<dim3(1024), tb, 0, stream>>>(Qp, Kp, buf2, buf1);
        gemm_nt64<<<dim3(8, 64, 1), tb, 0, stream>>>(buf1, buf1, buf1, buf1, WT,
            bo, bo, bo, bo, Qp, Kp, buf2, out, 3);
    }
}

// Round 9
// 234.793 us; speedup vs baseline: 1.3010x; 1.3010x over previous
//
#include <hip/hip_runtime.h>

typedef unsigned short ushort_t;
typedef unsigned int uint_t;
typedef __attribute__((ext_vector_type(8))) short short8;
typedef __attribute__((ext_vector_type(4))) float floatx4;

#define QSCALE 0.03187936f  // (1/sqrt(2048)) * log2(e): quirk scale + exp2 fold

__device__ __forceinline__ ushort_t f2bf(float f) {
    union { float f; uint_t u; } c; c.f = f;
    uint_t u = c.u;
    return (ushort_t)((u + 0x7fffu + ((u >> 16) & 1u)) >> 16);  // RNE
}
__device__ __forceinline__ floatx4 mfma16x32(short8 a, short8 b, floatx4 c) {
    return __builtin_amdgcn_mfma_f32_16x16x32_bf16(a, b, c, 0, 0, 0);
}
__device__ __forceinline__ floatx4 zero4() { floatx4 z = {0.f, 0.f, 0.f, 0.f}; return z; }

// Async 16B global->LDS. Per-lane lds ptr = base + lane*16B slot (HW uses
// lane0's ptr as wave base and strides lane*16 — matches our linear slots).
__device__ __forceinline__ void gload16(const ushort_t* g, ushort_t* l) {
    __builtin_amdgcn_global_load_lds(
        (const __attribute__((address_space(1))) void*)g,
        (__attribute__((address_space(3))) void*)l, 16, 0, 0);
}

// ---------------------------------------------------------------------------
// f32 -> bf16 convert (RNE), 8 elems/thread, up to 3 tensors of 4M elems.
// ---------------------------------------------------------------------------
__global__ __launch_bounds__(256) void cvt_bf16(
    const float* __restrict__ s0, const float* __restrict__ s1,
    const float* __restrict__ s2, ushort_t* __restrict__ d0,
    ushort_t* __restrict__ d1, ushort_t* __restrict__ d2)
{
    const int which = blockIdx.x >> 11;
    const int blk = blockIdx.x & 2047;
    const float* src = (which == 0) ? s0 : (which == 1) ? s1 : s2;
    ushort_t* dst = (which == 0) ? d0 : (which == 1) ? d1 : d2;
    const int i = (blk * 256 + threadIdx.x) * 8;
    float4 f0 = *(const float4*)(src + i);
    float4 f1 = *(const float4*)(src + i + 4);
    __align__(16) ushort_t t[8];
    t[0] = f2bf(f0.x); t[1] = f2bf(f0.y); t[2] = f2bf(f0.z); t[3] = f2bf(f0.w);
    t[4] = f2bf(f1.x); t[5] = f2bf(f1.y); t[6] = f2bf(f1.z); t[7] = f2bf(f1.w);
    *(uint4*)(dst + i) = *(uint4*)t;
}

// ---------------------------------------------------------------------------
// Fused convert+transpose: W[k][j] (1024x1024 f32) -> WT[j][k] bf16.
// ---------------------------------------------------------------------------
__global__ __launch_bounds__(256) void transpose_w(
    const float* __restrict__ W0, const float* __restrict__ W1,
    const float* __restrict__ W2, const float* __restrict__ W3,
    ushort_t* __restrict__ WT)
{
    __shared__ ushort_t tile[64][65];
    const float* W = (blockIdx.y == 0) ? W0 : (blockIdx.y == 1) ? W1
                   : (blockIdx.y == 2) ? W2 : W3;
    ushort_t* dst = WT + (size_t)blockIdx.y * (1024 * 1024);
    const int t = threadIdx.x;
    const int r = t >> 2, p = t & 3;
    const int j0 = (blockIdx.x & 15) << 6, k0 = (blockIdx.x >> 4) << 6;

    const float* src = W + (size_t)(k0 + r) * 1024 + j0 + p * 16;
    float4 f0 = *(const float4*)(src);
    float4 f1 = *(const float4*)(src + 4);
    float4 f2 = *(const float4*)(src + 8);
    float4 f3 = *(const float4*)(src + 12);
    ushort_t* tr = &tile[r][p * 16];
    tr[0] = f2bf(f0.x); tr[1] = f2bf(f0.y); tr[2]  = f2bf(f0.z); tr[3]  = f2bf(f0.w);
    tr[4] = f2bf(f1.x); tr[5] = f2bf(f1.y); tr[6]  = f2bf(f1.z); tr[7]  = f2bf(f1.w);
    tr[8] = f2bf(f2.x); tr[9] = f2bf(f2.y); tr[10] = f2bf(f2.z); tr[11] = f2bf(f2.w);
    tr[12] = f2bf(f3.x); tr[13] = f2bf(f3.y); tr[14] = f2bf(f3.z); tr[15] = f2bf(f3.w);
    __syncthreads();
    __align__(16) ushort_t buf[16];
#pragma unroll
    for (int i = 0; i < 16; ++i) buf[i] = tile[p * 16 + i][r];
    ushort_t* o = dst + (size_t)(j0 + r) * 1024 + k0 + p * 16;
    *(uint4*)(o)     = *(uint4*)(buf);
    *(uint4*)(o + 8) = *(uint4*)(buf + 8);
}

// ---------------------------------------------------------------------------
// Projection GEMM: C[r][c] = sum_k A[r][k]*WT[c][k] + bias[c]. 4096x1024x1024.
// 128x128 tile, BK=32, global_load_lds staging, XOR-swizzled LDS chunks.
// mode = blockIdx.z + zbase: 0: Q -> [B,H,S,64] *QSCALE; 1: K -> [B,H,S,64];
// 2: V -> [B,H,64,S].
// ---------------------------------------------------------------------------
__global__ __launch_bounds__(256) void gemm_bt(
    const ushort_t* __restrict__ A0, const ushort_t* __restrict__ A1,
    const ushort_t* __restrict__ A2, const ushort_t* __restrict__ WT,
    const float* __restrict__ b0, const float* __restrict__ b1,
    const float* __restrict__ b2,
    ushort_t* __restrict__ Dq, ushort_t* __restrict__ Dk,
    ushort_t* __restrict__ Dv, int zbase)
{
    __shared__ __align__(16) ushort_t As[128 * 32];
    __shared__ __align__(16) ushort_t Bs[128 * 32];

    const int mode = blockIdx.z + zbase;
    const ushort_t* A = (mode == 0) ? A0 : (mode == 1) ? A1 : A2;
    const float* bias = (mode == 0) ? b0 : (mode == 1) ? b1 : b2;
    const ushort_t* Bt = WT + (size_t)mode * 1048576;

    const int tid = threadIdx.x;
    const int lane = tid & 63, wid = tid >> 6;
    const int quad = lane >> 4, l16 = lane & 15;
    const int wm = wid >> 1, wn = wid & 1;
    const int row0 = blockIdx.y << 7, col0 = blockIdx.x << 7;

    floatx4 acc[4][4];
#pragma unroll
    for (int i = 0; i < 4; ++i)
#pragma unroll
        for (int j = 0; j < 4; ++j) acc[i][j] = zero4();

    const int i0 = tid, i1 = 256 + tid;
    const int r0_ = i0 >> 2, c0_ = (i0 & 3) ^ (r0_ & 3);
    const int r1_ = i1 >> 2, c1_ = (i1 & 3) ^ (r1_ & 3);
    const ushort_t* gA0 = A  + (size_t)(row0 + r0_) * 1024 + c0_ * 8;
    const ushort_t* gA1 = A  + (size_t)(row0 + r1_) * 1024 + c1_ * 8;
    const ushort_t* gB0 = Bt + (size_t)(col0 + r0_) * 1024 + c0_ * 8;
    const ushort_t* gB1 = Bt + (size_t)(col0 + r1_) * 1024 + c1_ * 8;
    ushort_t* lA0 = As + i0 * 8;  ushort_t* lA1 = As + i1 * 8;
    ushort_t* lB0 = Bs + i0 * 8;  ushort_t* lB1 = Bs + i1 * 8;

    const int ra = wm * 64 + l16, rb = wn * 64 + l16;
    const int sa_off = (quad ^ (l16 & 3)) * 8;

    for (int k0 = 0; k0 < 1024; k0 += 32) {
        __syncthreads();
        gload16(gA0 + k0, lA0);
        gload16(gA1 + k0, lA1);
        gload16(gB0 + k0, lB0);
        gload16(gB1 + k0, lB1);
        __syncthreads();

        short8 af[4], bf[4];
#pragma unroll
        for (int i = 0; i < 4; ++i)
            af[i] = *(const short8*)(As + (ra + i * 16) * 32 + sa_off);
#pragma unroll
        for (int j = 0; j < 4; ++j)
            bf[j] = *(const short8*)(Bs + (rb + j * 16) * 32 + sa_off);
#pragma unroll
        for (int i = 0; i < 4; ++i)
#pragma unroll
            for (int j = 0; j < 4; ++j)
                acc[i][j] = mfma16x32(af[i], bf[j], acc[i][j]);
    }

    const float sc = (mode == 0) ? QSCALE : 1.f;
#pragma unroll
    for (int i = 0; i < 4; ++i) {
#pragma unroll
        for (int j = 0; j < 4; ++j) {
            const int c = col0 + wn * 64 + j * 16 + l16;
            const float bv = bias[c];
#pragma unroll
            for (int rr = 0; rr < 4; ++rr) {
                const int r = row0 + wm * 64 + i * 16 + quad * 4 + rr;
                const float v = (acc[i][j][rr] + bv) * sc;
                const int b = r >> 11, s = r & 2047, h = c >> 6, d = c & 63;
                if (mode <= 1) {
                    ushort_t* D = (mode == 0) ? Dq : Dk;
                    D[(((b * 16 + h) * 2048 + s) << 6) + d] = f2bf(v);
                } else {
                    Dv[(((b * 16 + h) * 64 + d) << 11) + s] = f2bf(v);
                }
            }
        }
    }
}

// ---------------------------------------------------------------------------
// Output GEMM: Dout[r][c] = sum_k A[r][k]*WoT[c][k] + bias[c], f32 out.
// 64x128 tile -> 512 blocks (2 blocks/CU).
// ---------------------------------------------------------------------------
__global__ __launch_bounds__(256) void gemm64(
    const ushort_t* __restrict__ A, const ushort_t* __restrict__ Bt,
    const float* __restrict__ bias, float* __restrict__ Dout)
{
    __shared__ __align__(16) ushort_t As[64 * 32];
    __shared__ __align__(16) ushort_t Bs[128 * 32];
    const int tid = threadIdx.x;
    const int lane = tid & 63, wid = tid >> 6;
    const int quad = lane >> 4, l16 = lane & 15;
    const int wm = wid >> 1, wn = wid & 1;
    const int row0 = blockIdx.y << 6, col0 = blockIdx.x << 7;

    floatx4 acc[2][4];
#pragma unroll
    for (int i = 0; i < 2; ++i)
#pragma unroll
        for (int j = 0; j < 4; ++j) acc[i][j] = zero4();

    const int rA = tid >> 2, cA = (tid & 3) ^ (rA & 3);
    const ushort_t* gA = A + (size_t)(row0 + rA) * 1024 + cA * 8;
    ushort_t* lA = As + tid * 8;
    const int i0 = tid, i1 = 256 + tid;
    const int rB0 = i0 >> 2, cB0 = (i0 & 3) ^ (rB0 & 3);
    const int rB1 = i1 >> 2, cB1 = (i1 & 3) ^ (rB1 & 3);
    const ushort_t* gB0 = Bt + (size_t)(col0 + rB0) * 1024 + cB0 * 8;
    const ushort_t* gB1 = Bt + (size_t)(col0 + rB1) * 1024 + cB1 * 8;
    ushort_t* lB0 = Bs + i0 * 8;  ushort_t* lB1 = Bs + i1 * 8;

    const int sa_off = (quad ^ (l16 & 3)) * 8;

    for (int k0 = 0; k0 < 1024; k0 += 32) {
        __syncthreads();
        gload16(gA + k0, lA);
        gload16(gB0 + k0, lB0);
        gload16(gB1 + k0, lB1);
        __syncthreads();

        short8 af[2], bf[4];
#pragma unroll
        for (int i = 0; i < 2; ++i)
            af[i] = *(const short8*)(As + (wm * 32 + i * 16 + l16) * 32 + sa_off);
#pragma unroll
        for (int j = 0; j < 4; ++j)
            bf[j] = *(const short8*)(Bs + (wn * 64 + j * 16 + l16) * 32 + sa_off);
#pragma unroll
        for (int i = 0; i < 2; ++i)
#pragma unroll
            for (int j = 0; j < 4; ++j)
                acc[i][j] = mfma16x32(af[i], bf[j], acc[i][j]);
    }

#pragma unroll
    for (int i = 0; i < 2; ++i)
#pragma unroll
        for (int j = 0; j < 4; ++j) {
            const int c = col0 + wn * 64 + j * 16 + l16;
            const float bv = bias[c];
#pragma unroll
            for (int rr = 0; rr < 4; ++rr) {
                const int r = row0 + wm * 32 + i * 16 + quad * 4 + rr;
                Dout[(size_t)r * 1024 + c] = acc[i][j][rr] + bv;
            }
        }
}

// ---------------------------------------------------------------------------
// Attention (R7 kernel body, BK=64, VGPR~36) with XCD-affinity 1D grid:
// bh = blk & 31 -> XCD = blk % 8 = bh % 8, so each XCD serves 4 heads
// (4 x 512KB K+V = 2MB, resident in its 4MB L2).
// S^T = K·Q^T: lane (l16,quad) holds P[qrow=l16][kcol=g*16+quad*4+r].
// PV: K=32 MFMA, slots j=0..3 <- g-block 2G, j=4..7 <- g-block 2G+1, on
// both A (packed P) and B (two b64 V reads). Fixed-shift softmax:
// p = exp2(min(s,80)), truncated to bf16, denominator sums truncated values.
// ---------------------------------------------------------------------------
__global__ __launch_bounds__(256, 4) void attn64(
    const ushort_t* __restrict__ Q, const ushort_t* __restrict__ K,
    const ushort_t* __restrict__ Vt, ushort_t* __restrict__ Out)
{
    __shared__ __align__(16) ushort_t Ks[64 * 64];  // [kcol][d], swizzled chunks
    __shared__ __align__(16) ushort_t Vs[64 * 64];  // [d][kcol], swizzled chunks

    const int tid = threadIdx.x;
    const int lane = tid & 63, wid = tid >> 6;
    const int quad = lane >> 4, l16 = lane & 15;
    const int blk = blockIdx.x;
    const int bh = blk & 31;          // head-major: XCD = blk%8 = bh%8
    const int q0 = (blk >> 5) << 6;

    const ushort_t* Qh = Q + (size_t)bh * (2048 * 64);
    const ushort_t* Kh = K + (size_t)bh * (2048 * 64);
    const ushort_t* Vh = Vt + (size_t)bh * (64 * 2048);

    const int qr = q0 + wid * 16 + l16;
    const short8 qf0 = *(const short8*)(Qh + (size_t)qr * 64 + quad * 8);
    const short8 qf1 = *(const short8*)(Qh + (size_t)qr * 64 + 32 + quad * 8);

    float l_st = 0.f;
    floatx4 o_acc[4];
#pragma unroll
    for (int d = 0; d < 4; ++d) o_acc[d] = zero4();

    const int i0 = tid, i1 = 256 + tid;
    const int kr0 = i0 >> 3, kc0 = (i0 & 7) ^ (kr0 & 7);
    const int kr1 = i1 >> 3, kc1 = (i1 & 7) ^ (kr1 & 7);
    const ushort_t* gK0 = Kh + (size_t)kr0 * 64 + kc0 * 8;
    const ushort_t* gK1 = Kh + (size_t)kr1 * 64 + kc1 * 8;
    const ushort_t* gV0 = Vh + (size_t)kr0 * 2048 + kc0 * 8;
    const ushort_t* gV1 = Vh + (size_t)kr1 * 2048 + kc1 * 8;
    ushort_t* lK0 = Ks + i0 * 8;  ushort_t* lK1 = Ks + i1 * 8;
    ushort_t* lV0 = Vs + i0 * 8;  ushort_t* lV1 = Vs + i1 * 8;

    const int l7 = l16 & 7;
    const int q2 = quad >> 1, q1 = (quad & 1) * 4;

    for (int kt = 0; kt < 2048; kt += 64) {
        __syncthreads();
        gload16(gK0 + (size_t)kt * 64, lK0);
        gload16(gK1 + (size_t)kt * 64, lK1);
        gload16(gV0 + kt, lV0);
        gload16(gV1 + kt, lV1);
        __syncthreads();

        // S^T tiles: A = K-frag (m=kcol), B = Q-frag (n=qrow)
        floatx4 sa[4];
#pragma unroll
        for (int g = 0; g < 4; ++g) {
            const int row = g * 16 + l16;  // kcol
            const short8 kf0 = *(const short8*)(Ks + row * 64 + ((quad ^ l7) * 8));
            const short8 kf1 = *(const short8*)(Ks + row * 64 + (((quad + 4) ^ l7) * 8));
            sa[g] = mfma16x32(kf0, qf0, zero4());
            sa[g] = mfma16x32(kf1, qf1, sa[g]);
        }

        // softmax + pack two g-blocks per K=32 PV MFMA (no padding waste)
#pragma unroll
        for (int G = 0; G < 2; ++G) {
            uint_t ub[8];
#pragma unroll
            for (int t = 0; t < 8; ++t) {
                const int g = G * 2 + (t >> 2), r = t & 3;
                const float e = __builtin_amdgcn_exp2f(fminf(sa[g][r], 80.f));
                const uint_t u = __float_as_uint(e) & 0xffff0000u;
                l_st += __uint_as_float(u);   // sum the TRUNCATED value
                ub[t] = u;
            }
            union { uint_t u[4]; short8 s; } pc;
            pc.u[0] = (ub[0] >> 16) | ub[1];
            pc.u[1] = (ub[2] >> 16) | ub[3];
            pc.u[2] = (ub[4] >> 16) | ub[5];
            pc.u[3] = (ub[6] >> 16) | ub[7];
            const short8 pf = pc.s;

            const int ch0 = ((4 * G + q2) ^ l7) * 8;
            const int ch1 = ((4 * G + 2 + q2) ^ l7) * 8;
#pragma unroll
            for (int db = 0; db < 4; ++db) {
                const int vbase = (db * 16 + l16) * 64 + q1;
                const uint2 v0 = *(const uint2*)(Vs + vbase + ch0);
                const uint2 v1 = *(const uint2*)(Vs + vbase + ch1);
                union { uint_t u[4]; short8 s; } vc;
                vc.u[0] = v0.x; vc.u[1] = v0.y; vc.u[2] = v1.x; vc.u[3] = v1.y;
                o_acc[db] = mfma16x32(pf, vc.s, o_acc[db]);
            }
        }
    }

    // denominator: sum across the 4 quads sharing qrow=l16
    l_st += __shfl_xor(l_st, 16);
    l_st += __shfl_xor(l_st, 32);

    const int b = bh >> 4, h = bh & 15;
    const int s0 = q0 + wid * 16 + quad * 4;
#pragma unroll
    for (int r = 0; r < 4; ++r) {
        const float lr = __shfl(l_st, quad * 4 + r);  // l of qrow quad*4+r
        const float inv = 1.f / lr;
#pragma unroll
        for (int db = 0; db < 4; ++db) {
            const float v = o_acc[db][r] * inv;
            Out[(size_t)(b * 2048 + s0 + r) * 1024 + h * 64 + db * 16 + l16] = f2bf(v);
        }
    }
}

// ---------------------------------------------------------------------------
// Launch (R7 structure; attn grid is now 1D/1024 with head-major XCD swizzle).
//  big (>=64MiB): WT@0 Qb@8M Kb@16M Vb@24M Qp@32M Kp@40M Vtp@48M An@56M
//  small (40MiB): WT@0 buf1@8M buf2@16M Qp@24M Kp@32M
// ---------------------------------------------------------------------------
extern "C" void kernel_launch(void* const* d_in, const int* in_sizes, int n_in,
                              void* d_out, int out_size, void* d_ws, size_t ws_size,
                              hipStream_t stream) {
    const float* queries = (const float*)d_in[0];
    const float* keys    = (const float*)d_in[1];
    const float* values  = (const float*)d_in[2];
    const float* Wq = (const float*)d_in[3];
    const float* bq = (const float*)d_in[4];
    const float* Wk = (const float*)d_in[5];
    const float* bk = (const float*)d_in[6];
    const float* Wv = (const float*)d_in[7];
    const float* bv = (const float*)d_in[8];
    const float* Wo = (const float*)d_in[9];
    const float* bo = (const float*)d_in[10];
    float* out = (float*)d_out;

    char* ws = (char*)d_ws;
    const size_t MB = 1024 * 1024;
    ushort_t* WT = (ushort_t*)(ws);
    const ushort_t* WoT = WT + 3 * 1048576;
    dim3 tb(256);

    transpose_w<<<dim3(256, 4), tb, 0, stream>>>(Wq, Wk, Wv, Wo, WT);

    if (ws_size >= 64 * MB) {
        ushort_t* Qb  = (ushort_t*)(ws + 8 * MB);
        ushort_t* Kb  = (ushort_t*)(ws + 16 * MB);
        ushort_t* Vb  = (ushort_t*)(ws + 24 * MB);
        ushort_t* Qp  = (ushort_t*)(ws + 32 * MB);
        ushort_t* Kp  = (ushort_t*)(ws + 40 * MB);
        ushort_t* Vtp = (ushort_t*)(ws + 48 * MB);
        ushort_t* An  = (ushort_t*)(ws + 56 * MB);
        cvt_bf16<<<dim3(6144), tb, 0, stream>>>(queries, keys, values, Qb, Kb, Vb);
        gemm_bt<<<dim3(8, 32, 3), tb, 0, stream>>>(Qb, Kb, Vb, WT,
            bq, bk, bv, Qp, Kp, Vtp, 0);
        attn64<<<dim3(1024), tb, 0, stream>>>(Qp, Kp, Vtp, An);
        gemm64<<<dim3(8, 64), tb, 0, stream>>>(An, WoT, bo, out);
    } else {
        ushort_t* buf1 = (ushort_t*)(ws + 8 * MB);
        ushort_t* buf2 = (ushort_t*)(ws + 16 * MB);
        ushort_t* Qp   = (ushort_t*)(ws + 24 * MB);
        ushort_t* Kp   = (ushort_t*)(ws + 32 * MB);
        cvt_bf16<<<dim3(4096), tb, 0, stream>>>(queries, keys, keys, buf1, buf2, buf2);
        gemm_bt<<<dim3(8, 32, 2), tb, 0, stream>>>(buf1, buf2, buf2, WT,
            bq, bk, bk, Qp, Kp, Kp, 0);
        cvt_bf16<<<dim3(2048), tb, 0, stream>>>(values, values, values, buf1, buf1, buf1);
        gemm_bt<<<dim3(8, 32, 1), tb, 0, stream>>>(buf1, buf1, buf1, WT,
            bv, bv, bv, buf2, buf2, buf2, 2);   // mode 2: V -> Vtp = buf2
        attn64<<<dim3(1024), tb, 0, stream>>>(Qp, Kp, buf2, buf1);
        gemm64<<<dim3(8, 64), tb, 0, stream>>>(buf1, WoT, bo, out);
    }
}